// Round 11
// baseline (111.140 us; speedup 1.0000x reference)
//
#include <hip/hip_runtime.h>
#include <math.h>

// R16 = R15 + PROLOGUE-BATCHED SINCOS: all 20 neuron phases phih(ln,wv) are
// computed in one independent batch at block start (perfect ILP: 40 ds_reads
// + 20 adds + 40 trans, latency fully pipelined) and held in REGISTERS
// (sN/cN, compile-time-indexed only -> no scratch). Each neuron's head
// becomes two register reads: the ds_read(~120cy)+sincos(~40cy) serial head
// is removed from every one of the 20 sequential neuron chains.
// Evidence: R15's head cut (s_load tree -> ds_read+add) gave the first
// positive delta (-1.4us) after five math-body nulls -> chains are
// head-latency-bound. VGPR 60 -> ~100 (cap 128; occupancy is grid-limited
// at 2 blocks/CU, so free).
//   flat bits [11:6] = lane (q0..q5), [5:3] = wave (q6..q8), [2:0] = reg.

typedef float v2f __attribute__((ext_vector_type(2)));

#define NSLOT 512  // 8 waves * 64 lanes

__device__ __forceinline__ v2f mk(float a, float b) { v2f r; r.x = a; r.y = b; return r; }

// native sincos: v_sin_f32/v_cos_f32 take revolutions (D = sin(S0*2pi)).
__device__ __forceinline__ void fast_sincos(float a, float* s, float* c) {
    float r = a * 0.15915494309189535f;  // 1/(2*pi)
    *s = __builtin_amdgcn_sinf(r);
    *c = __builtin_amdgcn_cosf(r);
}

// cross-lane xor shuffle; VALU (DPP/permlane) everywhere except xor4.
template <int XM>
__device__ __forceinline__ float shx(float x, int ln) {
    if constexpr (XM == 1) {        // quad_perm [1,0,3,2] = xor 1 (VALU)
        return __int_as_float(__builtin_amdgcn_update_dpp(
            0, __float_as_int(x), 0xB1, 0xF, 0xF, true));
    } else if constexpr (XM == 2) { // quad_perm [2,3,0,1] = xor 2 (VALU)
        return __int_as_float(__builtin_amdgcn_update_dpp(
            0, __float_as_int(x), 0x4E, 0xF, 0xF, true));
    } else if constexpr (XM == 8) { // row_ror:8 -> i^8 within 16 rows (VALU)
        return __int_as_float(__builtin_amdgcn_update_dpp(
            0, __float_as_int(x), 0x128, 0xF, 0xF, true));
    } else if constexpr (XM == 4) { // ds_swizzle BitMode: lane' = lane ^ 4
        return __int_as_float(__builtin_amdgcn_ds_swizzle(
            __float_as_int(x), 0x101F));
    } else if constexpr (XM == 16) {
#if __has_builtin(__builtin_amdgcn_permlane16_swap)
        auto r = __builtin_amdgcn_permlane16_swap(
            __float_as_int(x), __float_as_int(x), false, false);
        return __int_as_float((ln & 16) ? r[0] : r[1]);
#else
        return __int_as_float(__builtin_amdgcn_ds_swizzle(
            __float_as_int(x), 0x401F));
#endif
    } else {                        // XM == 32
#if __has_builtin(__builtin_amdgcn_permlane32_swap)
        auto r = __builtin_amdgcn_permlane32_swap(
            __float_as_int(x), __float_as_int(x), false, false);
        return __int_as_float((ln & 32) ? r[0] : r[1]);
#else
        return __shfl_xor(x, 32, 64);
#endif
    }
}

template <int LM>
__device__ __forceinline__ void lane_ry_t(v2f (&V)[4], float c, float s, int ln) {
    float ss = (ln & LM) ? s : -s;
#pragma unroll
    for (int k = 0; k < 4; ++k) {
        v2f p = mk(shx<LM>(V[k].x, ln), shx<LM>(V[k].y, ln));
        V[k] = c * V[k] + ss * p;
    }
}

// merged 3-qubit cross-wave rotation R(q6)R(q7)R(q8) (commuting):
// one full-state LDS write + ONE barrier + 8-point gather per thread.
__device__ __forceinline__ void wave_ry3(v2f (&V)[4],
                                         float c4, float s4,
                                         float c2, float s2,
                                         float c1, float s1,
                                         int wv, int ln, float4* buf) {
    const int slot = wv * 64 + ln;
    buf[slot]         = make_float4(V[0].x, V[0].y, V[1].x, V[1].y);
    buf[NSLOT + slot] = make_float4(V[2].x, V[2].y, V[3].x, V[3].y);

    const float A4 = (wv & 4) ? s4 : c4,  B4 = (wv & 4) ? c4 : -s4;
    const float A2 = (wv & 2) ? s2 : c2,  B2 = (wv & 2) ? c2 : -s2;
    const float A1 = (wv & 1) ? s1 : c1,  B1 = (wv & 1) ? c1 : -s1;

    __syncthreads();

    v2f a0 = mk(0.f, 0.f), a1 = a0, a2 = a0, a3 = a0;
#pragma unroll
    for (int pv = 0; pv < 8; ++pv) {
        const float k = ((pv & 4) ? B4 : A4) *
                        ((pv & 2) ? B2 : A2) *
                        ((pv & 1) ? B1 : A1);
        float4 t0 = buf[pv * 64 + ln];
        float4 t1 = buf[NSLOT + pv * 64 + ln];
        a0 += k * mk(t0.x, t0.y);
        a1 += k * mk(t0.z, t0.w);
        a2 += k * mk(t1.x, t1.y);
        a3 += k * mk(t1.z, t1.w);
    }
    V[0] = a0; V[1] = a1; V[2] = a2; V[3] = a3;
}

// Delta-form quantum neuron; (sA,cA) pre-computed in the prologue batch,
// B-angle via angle addition from trigN (4 FMA).
template <int OUT>
__device__ __forceinline__ void neuron(v2f (&V)[4], float sA, float cA,
                                       const float2* __restrict__ trigN,
                                       int wv, int ln, float4* buf) {
    float2 t9 = trigN[OUT];
    float sB = sA * t9.x + cA * t9.y;   // sin(phih + 0.5*th9)
    float cB = cA * t9.x - sA * t9.y;   // cos(phih + 0.5*th9)

    // y-only half1
    float tyA = cA * V[0].y - sA * V[1].y;
    float txA = sA * V[0].x + cA * V[1].x;
    float uA0 =  cA * tyA + sA * txA;
    float uA1 = -sA * tyA + cA * txA;
    float tyB = cB * V[2].y - sB * V[3].y;
    float txB = sB * V[2].x + cB * V[3].x;
    float uB0 =  cB * tyB + sB * txB;
    float uB1 = -sB * tyB + cB * txB;

    float dA0, dA1, dB0, dB1;
    if constexpr (OUT < 6) {
        constexpr int LM = 1 << (5 - OUT);
        float ssn = (ln & LM) ? 1.f : -1.f;
        dA0 = fmaf(ssn, shx<LM>(uA0, ln), -uA0);
        dA1 = fmaf(ssn, shx<LM>(uA1, ln), -uA1);
        dB0 = fmaf(ssn, shx<LM>(uB0, ln), -uB0);
        dB1 = fmaf(ssn, shx<LM>(uB1, ln), -uB1);
    } else if constexpr (OUT < 9) {
        constexpr int WM = 1 << (8 - OUT);
        const int slot = wv * 64 + ln;
        buf[slot] = make_float4(uA0, uA1, uB0, uB1);
        __syncthreads();
        const int pslot = (wv ^ WM) * 64 + ln;
        float ssn = (wv & WM) ? 1.f : -1.f;
        float4 t = buf[pslot];
        dA0 = fmaf(ssn, t.x, -uA0); dA1 = fmaf(ssn, t.y, -uA1);
        dB0 = fmaf(ssn, t.z, -uB0); dB1 = fmaf(ssn, t.w, -uB1);
    } else {  // OUT == 9: new(A) = -old(B), new(B) = old(A)
        dA0 = -uB0 - uA0; dA1 = -uB1 - uA1;
        dB0 =  uA0 - uB0; dB1 =  uA1 - uB1;
    }

    // v += M2 * Delta  (M2 = half2 matrix; Delta only on y comps)
    float eA = sA * dA0 + cA * dA1, fA = cA * dA0 - sA * dA1;
    V[0].x += sA * eA; V[0].y += cA * fA;
    V[1].x += cA * eA; V[1].y -= sA * fA;
    float eB = sB * dB0 + cB * dB1, fB = cB * dB0 - sB * dB1;
    V[2].x += sB * eB; V[2].y += cB * fB;
    V[3].x += cB * eB; V[3].y -= sB * fB;
}

__global__ __launch_bounds__(512, 4) void rvqe_kernel(
    const float* __restrict__ psi_in,   // (B, 4096)
    const int*   __restrict__ inp,      // (6,)
    const float* __restrict__ ut,       // (2, 10)
    const float* __restrict__ nt,       // (2, 10, 11)
    float* __restrict__ out_probs,      // (B, 64)
    float* __restrict__ out_psi)        // (B, 4096)
{
    __shared__ float4 xbuf[2][2 * NSLOT];  // 32 KB
    __shared__ float  asum[20][64];        // 5 KB: 0.5*sum sel th[0..5]
    __shared__ float  wsum[20][8];         // 640 B: 0.5*(th10 + sel th[6..8])
    __shared__ float2 trig[40];            // unitary (c,s); neuron th9 (c,s)

    const int b   = blockIdx.x;
    const int tid = threadIdx.x;
    const int ln  = tid & 63;
    const int wv  = tid >> 6;   // bit2=q6, bit1=q7, bit0=q8
    int bi = 0;

    // ---- prologue 1: build phase/trig tables (once per block) ----
#pragma unroll
    for (int idx = tid; idx < 1280; idx += 512) {
        int combo = idx >> 6;       // s*10+out
        int lane  = idx & 63;
        const float* th = nt + (combo / 10) * 110 + (combo % 10) * 11;
        float a = 0.f;
        if (lane & 32) a += th[0];
        if (lane & 16) a += th[1];
        if (lane &  8) a += th[2];
        if (lane &  4) a += th[3];
        if (lane &  2) a += th[4];
        if (lane &  1) a += th[5];
        asum[combo][lane] = 0.5f * a;
    }
    if (tid < 160) {
        int combo = tid >> 3;       // s*10+out
        int w = tid & 7;
        const float* th = nt + (combo / 10) * 110 + (combo % 10) * 11;
        float x = th[10];
        if (w & 4) x += th[6];
        if (w & 2) x += th[7];
        if (w & 1) x += th[8];
        wsum[combo][w] = 0.5f * x;
    }
    if (tid < 40) {
        float ang = (tid < 20) ? ut[tid]
                               : nt[((tid - 20) / 10) * 110 + ((tid - 20) % 10) * 11 + 9];
        float s, c;
        fast_sincos(0.5f * ang, &s, &c);
        trig[tid] = make_float2(c, s);
    }

    // BitFlip: fold X on input lanes into load address
    int flip = 0;
#pragma unroll
    for (int l = 0; l < 6; ++l)
        if (inp[l] == 1) flip |= 1 << (5 - l);

    v2f V[4];
    {
        const float* src = psi_in + (size_t)b * 4096 + (((ln ^ flip) & 63) << 6) + (wv << 3);
        float4 t0 = ((const float4*)src)[0];
        float4 t1 = ((const float4*)src)[1];
        V[0] = mk(t0.x, t0.y); V[1] = mk(t0.z, t0.w);
        V[2] = mk(t1.x, t1.y); V[3] = mk(t1.z, t1.w);
    }

    __syncthreads();  // tables ready

    // ---- prologue 2: batch ALL 20 neuron sincos into registers ----
    // (independent chains; compile-time indices only -> stays in VGPRs)
    float sN[20], cN[20];
#pragma unroll
    for (int k = 0; k < 20; ++k) {
        float ph = asum[k][ln] + wsum[k][wv];
        fast_sincos(ph, &sN[k], &cN[k]);
    }

#pragma unroll 1
    for (int s = 0; s < 2; ++s) {
        const float2* trigU = trig + s * 10;
        const float2* trigN = trig + 20 + s * 10;

        // ---- UnitaryLayer (all angles from LDS table) ----
        {
            float2 cs;
            cs = trigU[0]; lane_ry_t<32>(V, cs.x, cs.y, ln);
            cs = trigU[1]; lane_ry_t<16>(V, cs.x, cs.y, ln);
            cs = trigU[2]; lane_ry_t<8>(V, cs.x, cs.y, ln);
            cs = trigU[3]; lane_ry_t<4>(V, cs.x, cs.y, ln);
            cs = trigU[4]; lane_ry_t<2>(V, cs.x, cs.y, ln);
            cs = trigU[5]; lane_ry_t<1>(V, cs.x, cs.y, ln);
            float2 c6 = trigU[6], c7 = trigU[7], c8 = trigU[8];
            wave_ry3(V, c6.x, c6.y, c7.x, c7.y, c8.x, c8.y, wv, ln, xbuf[bi]); bi ^= 1;
            float2 c9 = trigU[9];
            v2f n0 = c9.x * V[0] - c9.y * V[2];
            v2f n2 = c9.y * V[0] + c9.x * V[2];
            v2f n1 = c9.x * V[1] - c9.y * V[3];
            v2f n3 = c9.y * V[1] + c9.x * V[3];
            V[0] = n0; V[1] = n1; V[2] = n2; V[3] = n3;
        }

        // ---- QuantumNeuronLayer, delta-form, register-resident heads ----
        if (s == 0) {
            neuron<0>(V, sN[0], cN[0], trigN, wv, ln, nullptr);
            neuron<1>(V, sN[1], cN[1], trigN, wv, ln, nullptr);
            neuron<2>(V, sN[2], cN[2], trigN, wv, ln, nullptr);
            neuron<3>(V, sN[3], cN[3], trigN, wv, ln, nullptr);
            neuron<4>(V, sN[4], cN[4], trigN, wv, ln, nullptr);
            neuron<5>(V, sN[5], cN[5], trigN, wv, ln, nullptr);
            neuron<6>(V, sN[6], cN[6], trigN, wv, ln, xbuf[bi]); bi ^= 1;
            neuron<7>(V, sN[7], cN[7], trigN, wv, ln, xbuf[bi]); bi ^= 1;
            neuron<8>(V, sN[8], cN[8], trigN, wv, ln, xbuf[bi]); bi ^= 1;
            neuron<9>(V, sN[9], cN[9], trigN, wv, ln, nullptr);
        } else {
            neuron<0>(V, sN[10], cN[10], trigN, wv, ln, nullptr);
            neuron<1>(V, sN[11], cN[11], trigN, wv, ln, nullptr);
            neuron<2>(V, sN[12], cN[12], trigN, wv, ln, nullptr);
            neuron<3>(V, sN[13], cN[13], trigN, wv, ln, nullptr);
            neuron<4>(V, sN[14], cN[14], trigN, wv, ln, nullptr);
            neuron<5>(V, sN[15], cN[15], trigN, wv, ln, nullptr);
            neuron<6>(V, sN[16], cN[16], trigN, wv, ln, xbuf[bi]); bi ^= 1;
            neuron<7>(V, sN[17], cN[17], trigN, wv, ln, xbuf[bi]); bi ^= 1;
            neuron<8>(V, sN[18], cN[18], trigN, wv, ln, xbuf[bi]); bi ^= 1;
            neuron<9>(V, sN[19], cN[19], trigN, wv, ln, nullptr);
        }
    }

    // ---- probs: marginal |amp|^2 over qubits 6..11 ----
    float acc = 0.f;
#pragma unroll
    for (int k = 0; k < 4; ++k) acc += V[k].x * V[k].x + V[k].y * V[k].y;
    {
        float* pb = (float*)&xbuf[bi][0];  // dbuf invariant holds
        pb[wv * 64 + ln] = acc;
        __syncthreads();
        if (wv == 0) {
            float t = 0.f;
#pragma unroll
            for (int w = 0; w < 8; ++w) t += pb[w * 64 + ln];
            out_probs[(size_t)b * 64 + ln] = t;
        }
    }

    // ---- write final psi ----
    float* dst = out_psi + (size_t)b * 4096 + (ln << 6) + (wv << 3);
    ((float4*)dst)[0] = make_float4(V[0].x, V[0].y, V[1].x, V[1].y);
    ((float4*)dst)[1] = make_float4(V[2].x, V[2].y, V[3].x, V[3].y);
}

extern "C" void kernel_launch(void* const* d_in, const int* in_sizes, int n_in,
                              void* d_out, int out_size, void* d_ws, size_t ws_size,
                              hipStream_t stream) {
    const float* psi = (const float*)d_in[0];
    const int*   inp = (const int*)d_in[1];
    const float* ut  = (const float*)d_in[2];
    const float* nt  = (const float*)d_in[3];

    const int B = in_sizes[0] >> 12;          // 4096 amplitudes per state
    float* probs = (float*)d_out;             // (B, 64) first
    float* opsi  = probs + (size_t)B * 64;    // then (B, 4096)

    rvqe_kernel<<<B, 512, 0, stream>>>(psi, inp, ut, nt, probs, opsi);
}

// Round 12
// 82.169 us; speedup vs baseline: 1.3526x; 1.3526x over previous
//
#include <hip/hip_runtime.h>
#include <math.h>

// R17 = R15 + PER-STAGE batched neuron sincos in NAMED SCALARS.
// R16 post-mortem: batching all 20 pairs in arrays spilled (~113 dw/thread
// scratch, WRITE_SIZE 119MB) because the allocator pins 512-thread kernels
// at 64 VGPR (8 waves/EU target). Fix: batch 10 pairs per stage as named
// scalars (mem2reg-promotable, ~20 extra live floats -> peak ~60 VGPR).
// The batch sits at stage head so its ds_read+trans latency pipelines under
// the independent unitary-layer math; every neuron chain then starts from
// two register reads instead of ds_read(120cy)+sincos(40cy).
//   flat bits [11:6] = lane (q0..q5), [5:3] = wave (q6..q8), [2:0] = reg.

typedef float v2f __attribute__((ext_vector_type(2)));

#define NSLOT 512  // 8 waves * 64 lanes

__device__ __forceinline__ v2f mk(float a, float b) { v2f r; r.x = a; r.y = b; return r; }

// native sincos: v_sin_f32/v_cos_f32 take revolutions (D = sin(S0*2pi)).
__device__ __forceinline__ void fast_sincos(float a, float* s, float* c) {
    float r = a * 0.15915494309189535f;  // 1/(2*pi)
    *s = __builtin_amdgcn_sinf(r);
    *c = __builtin_amdgcn_cosf(r);
}

// cross-lane xor shuffle; VALU (DPP/permlane) everywhere except xor4.
template <int XM>
__device__ __forceinline__ float shx(float x, int ln) {
    if constexpr (XM == 1) {        // quad_perm [1,0,3,2] = xor 1 (VALU)
        return __int_as_float(__builtin_amdgcn_update_dpp(
            0, __float_as_int(x), 0xB1, 0xF, 0xF, true));
    } else if constexpr (XM == 2) { // quad_perm [2,3,0,1] = xor 2 (VALU)
        return __int_as_float(__builtin_amdgcn_update_dpp(
            0, __float_as_int(x), 0x4E, 0xF, 0xF, true));
    } else if constexpr (XM == 8) { // row_ror:8 -> i^8 within 16 rows (VALU)
        return __int_as_float(__builtin_amdgcn_update_dpp(
            0, __float_as_int(x), 0x128, 0xF, 0xF, true));
    } else if constexpr (XM == 4) { // ds_swizzle BitMode: lane' = lane ^ 4
        return __int_as_float(__builtin_amdgcn_ds_swizzle(
            __float_as_int(x), 0x101F));
    } else if constexpr (XM == 16) {
#if __has_builtin(__builtin_amdgcn_permlane16_swap)
        auto r = __builtin_amdgcn_permlane16_swap(
            __float_as_int(x), __float_as_int(x), false, false);
        return __int_as_float((ln & 16) ? r[0] : r[1]);
#else
        return __int_as_float(__builtin_amdgcn_ds_swizzle(
            __float_as_int(x), 0x401F));
#endif
    } else {                        // XM == 32
#if __has_builtin(__builtin_amdgcn_permlane32_swap)
        auto r = __builtin_amdgcn_permlane32_swap(
            __float_as_int(x), __float_as_int(x), false, false);
        return __int_as_float((ln & 32) ? r[0] : r[1]);
#else
        return __shfl_xor(x, 32, 64);
#endif
    }
}

template <int LM>
__device__ __forceinline__ void lane_ry_t(v2f (&V)[4], float c, float s, int ln) {
    float ss = (ln & LM) ? s : -s;
#pragma unroll
    for (int k = 0; k < 4; ++k) {
        v2f p = mk(shx<LM>(V[k].x, ln), shx<LM>(V[k].y, ln));
        V[k] = c * V[k] + ss * p;
    }
}

// merged 3-qubit cross-wave rotation R(q6)R(q7)R(q8) (commuting):
// one full-state LDS write + ONE barrier + 8-point gather per thread.
__device__ __forceinline__ void wave_ry3(v2f (&V)[4],
                                         float c4, float s4,
                                         float c2, float s2,
                                         float c1, float s1,
                                         int wv, int ln, float4* buf) {
    const int slot = wv * 64 + ln;
    buf[slot]         = make_float4(V[0].x, V[0].y, V[1].x, V[1].y);
    buf[NSLOT + slot] = make_float4(V[2].x, V[2].y, V[3].x, V[3].y);

    const float A4 = (wv & 4) ? s4 : c4,  B4 = (wv & 4) ? c4 : -s4;
    const float A2 = (wv & 2) ? s2 : c2,  B2 = (wv & 2) ? c2 : -s2;
    const float A1 = (wv & 1) ? s1 : c1,  B1 = (wv & 1) ? c1 : -s1;

    __syncthreads();

    v2f a0 = mk(0.f, 0.f), a1 = a0, a2 = a0, a3 = a0;
#pragma unroll
    for (int pv = 0; pv < 8; ++pv) {
        const float k = ((pv & 4) ? B4 : A4) *
                        ((pv & 2) ? B2 : A2) *
                        ((pv & 1) ? B1 : A1);
        float4 t0 = buf[pv * 64 + ln];
        float4 t1 = buf[NSLOT + pv * 64 + ln];
        a0 += k * mk(t0.x, t0.y);
        a1 += k * mk(t0.z, t0.w);
        a2 += k * mk(t1.x, t1.y);
        a3 += k * mk(t1.z, t1.w);
    }
    V[0] = a0; V[1] = a1; V[2] = a2; V[3] = a3;
}

// Delta-form quantum neuron; (sA,cA) pre-computed at stage head,
// B-angle via angle addition from trigN (4 FMA).
template <int OUT>
__device__ __forceinline__ void neuron(v2f (&V)[4], float sA, float cA,
                                       const float2* __restrict__ trigN,
                                       int wv, int ln, float4* buf) {
    float2 t9 = trigN[OUT];
    float sB = sA * t9.x + cA * t9.y;   // sin(phih + 0.5*th9)
    float cB = cA * t9.x - sA * t9.y;   // cos(phih + 0.5*th9)

    // y-only half1
    float tyA = cA * V[0].y - sA * V[1].y;
    float txA = sA * V[0].x + cA * V[1].x;
    float uA0 =  cA * tyA + sA * txA;
    float uA1 = -sA * tyA + cA * txA;
    float tyB = cB * V[2].y - sB * V[3].y;
    float txB = sB * V[2].x + cB * V[3].x;
    float uB0 =  cB * tyB + sB * txB;
    float uB1 = -sB * tyB + cB * txB;

    float dA0, dA1, dB0, dB1;
    if constexpr (OUT < 6) {
        constexpr int LM = 1 << (5 - OUT);
        float ssn = (ln & LM) ? 1.f : -1.f;
        dA0 = fmaf(ssn, shx<LM>(uA0, ln), -uA0);
        dA1 = fmaf(ssn, shx<LM>(uA1, ln), -uA1);
        dB0 = fmaf(ssn, shx<LM>(uB0, ln), -uB0);
        dB1 = fmaf(ssn, shx<LM>(uB1, ln), -uB1);
    } else if constexpr (OUT < 9) {
        constexpr int WM = 1 << (8 - OUT);
        const int slot = wv * 64 + ln;
        buf[slot] = make_float4(uA0, uA1, uB0, uB1);
        __syncthreads();
        const int pslot = (wv ^ WM) * 64 + ln;
        float ssn = (wv & WM) ? 1.f : -1.f;
        float4 t = buf[pslot];
        dA0 = fmaf(ssn, t.x, -uA0); dA1 = fmaf(ssn, t.y, -uA1);
        dB0 = fmaf(ssn, t.z, -uB0); dB1 = fmaf(ssn, t.w, -uB1);
    } else {  // OUT == 9: new(A) = -old(B), new(B) = old(A)
        dA0 = -uB0 - uA0; dA1 = -uB1 - uA1;
        dB0 =  uA0 - uB0; dB1 =  uA1 - uB1;
    }

    // v += M2 * Delta  (M2 = half2 matrix; Delta only on y comps)
    float eA = sA * dA0 + cA * dA1, fA = cA * dA0 - sA * dA1;
    V[0].x += sA * eA; V[0].y += cA * fA;
    V[1].x += cA * eA; V[1].y -= sA * fA;
    float eB = sB * dB0 + cB * dB1, fB = cB * dB0 - sB * dB1;
    V[2].x += sB * eB; V[2].y += cB * fB;
    V[3].x += cB * eB; V[3].y -= sB * fB;
}

__global__ __launch_bounds__(512, 4) void rvqe_kernel(
    const float* __restrict__ psi_in,   // (B, 4096)
    const int*   __restrict__ inp,      // (6,)
    const float* __restrict__ ut,       // (2, 10)
    const float* __restrict__ nt,       // (2, 10, 11)
    float* __restrict__ out_probs,      // (B, 64)
    float* __restrict__ out_psi)        // (B, 4096)
{
    __shared__ float4 xbuf[2][2 * NSLOT];  // 32 KB
    __shared__ float  asum[20][64];        // 5 KB: 0.5*sum sel th[0..5]
    __shared__ float  wsum[20][8];         // 640 B: 0.5*(th10 + sel th[6..8])
    __shared__ float2 trig[40];            // unitary (c,s); neuron th9 (c,s)

    const int b   = blockIdx.x;
    const int tid = threadIdx.x;
    const int ln  = tid & 63;
    const int wv  = tid >> 6;   // bit2=q6, bit1=q7, bit0=q8
    int bi = 0;

    // ---- prologue: build phase/trig tables (once per block) ----
#pragma unroll
    for (int idx = tid; idx < 1280; idx += 512) {
        int combo = idx >> 6;       // s*10+out
        int lane  = idx & 63;
        const float* th = nt + (combo / 10) * 110 + (combo % 10) * 11;
        float a = 0.f;
        if (lane & 32) a += th[0];
        if (lane & 16) a += th[1];
        if (lane &  8) a += th[2];
        if (lane &  4) a += th[3];
        if (lane &  2) a += th[4];
        if (lane &  1) a += th[5];
        asum[combo][lane] = 0.5f * a;
    }
    if (tid < 160) {
        int combo = tid >> 3;       // s*10+out
        int w = tid & 7;
        const float* th = nt + (combo / 10) * 110 + (combo % 10) * 11;
        float x = th[10];
        if (w & 4) x += th[6];
        if (w & 2) x += th[7];
        if (w & 1) x += th[8];
        wsum[combo][w] = 0.5f * x;
    }
    if (tid < 40) {
        float ang = (tid < 20) ? ut[tid]
                               : nt[((tid - 20) / 10) * 110 + ((tid - 20) % 10) * 11 + 9];
        float s, c;
        fast_sincos(0.5f * ang, &s, &c);
        trig[tid] = make_float2(c, s);
    }

    // BitFlip: fold X on input lanes into load address
    int flip = 0;
#pragma unroll
    for (int l = 0; l < 6; ++l)
        if (inp[l] == 1) flip |= 1 << (5 - l);

    v2f V[4];
    {
        const float* src = psi_in + (size_t)b * 4096 + (((ln ^ flip) & 63) << 6) + (wv << 3);
        float4 t0 = ((const float4*)src)[0];
        float4 t1 = ((const float4*)src)[1];
        V[0] = mk(t0.x, t0.y); V[1] = mk(t0.z, t0.w);
        V[2] = mk(t1.x, t1.y); V[3] = mk(t1.z, t1.w);
    }

    __syncthreads();  // tables ready

#pragma unroll 1
    for (int s = 0; s < 2; ++s) {
        const float2* trigU = trig + s * 10;
        const float2* trigN = trig + 20 + s * 10;
        const float (*as)[64] = asum + s * 10;
        const float (*ws)[8]  = wsum + s * 10;

        // ---- stage-head batch: 10 neuron sincos into NAMED registers ----
        // (independent; ds_read+trans latency hides under the unitary below)
        float sn0, cn0, sn1, cn1, sn2, cn2, sn3, cn3, sn4, cn4;
        float sn5, cn5, sn6, cn6, sn7, cn7, sn8, cn8, sn9, cn9;
        fast_sincos(as[0][ln] + ws[0][wv], &sn0, &cn0);
        fast_sincos(as[1][ln] + ws[1][wv], &sn1, &cn1);
        fast_sincos(as[2][ln] + ws[2][wv], &sn2, &cn2);
        fast_sincos(as[3][ln] + ws[3][wv], &sn3, &cn3);
        fast_sincos(as[4][ln] + ws[4][wv], &sn4, &cn4);
        fast_sincos(as[5][ln] + ws[5][wv], &sn5, &cn5);
        fast_sincos(as[6][ln] + ws[6][wv], &sn6, &cn6);
        fast_sincos(as[7][ln] + ws[7][wv], &sn7, &cn7);
        fast_sincos(as[8][ln] + ws[8][wv], &sn8, &cn8);
        fast_sincos(as[9][ln] + ws[9][wv], &sn9, &cn9);

        // ---- UnitaryLayer (all angles from LDS table) ----
        {
            float2 cs;
            cs = trigU[0]; lane_ry_t<32>(V, cs.x, cs.y, ln);
            cs = trigU[1]; lane_ry_t<16>(V, cs.x, cs.y, ln);
            cs = trigU[2]; lane_ry_t<8>(V, cs.x, cs.y, ln);
            cs = trigU[3]; lane_ry_t<4>(V, cs.x, cs.y, ln);
            cs = trigU[4]; lane_ry_t<2>(V, cs.x, cs.y, ln);
            cs = trigU[5]; lane_ry_t<1>(V, cs.x, cs.y, ln);
            float2 c6 = trigU[6], c7 = trigU[7], c8 = trigU[8];
            wave_ry3(V, c6.x, c6.y, c7.x, c7.y, c8.x, c8.y, wv, ln, xbuf[bi]); bi ^= 1;
            float2 c9 = trigU[9];
            v2f n0 = c9.x * V[0] - c9.y * V[2];
            v2f n2 = c9.y * V[0] + c9.x * V[2];
            v2f n1 = c9.x * V[1] - c9.y * V[3];
            v2f n3 = c9.y * V[1] + c9.x * V[3];
            V[0] = n0; V[1] = n1; V[2] = n2; V[3] = n3;
        }

        // ---- QuantumNeuronLayer, delta-form, register-resident heads ----
        neuron<0>(V, sn0, cn0, trigN, wv, ln, nullptr);
        neuron<1>(V, sn1, cn1, trigN, wv, ln, nullptr);
        neuron<2>(V, sn2, cn2, trigN, wv, ln, nullptr);
        neuron<3>(V, sn3, cn3, trigN, wv, ln, nullptr);
        neuron<4>(V, sn4, cn4, trigN, wv, ln, nullptr);
        neuron<5>(V, sn5, cn5, trigN, wv, ln, nullptr);
        neuron<6>(V, sn6, cn6, trigN, wv, ln, xbuf[bi]); bi ^= 1;
        neuron<7>(V, sn7, cn7, trigN, wv, ln, xbuf[bi]); bi ^= 1;
        neuron<8>(V, sn8, cn8, trigN, wv, ln, xbuf[bi]); bi ^= 1;
        neuron<9>(V, sn9, cn9, trigN, wv, ln, nullptr);
    }

    // ---- probs: marginal |amp|^2 over qubits 6..11 ----
    float acc = 0.f;
#pragma unroll
    for (int k = 0; k < 4; ++k) acc += V[k].x * V[k].x + V[k].y * V[k].y;
    {
        float* pb = (float*)&xbuf[bi][0];  // dbuf invariant holds
        pb[wv * 64 + ln] = acc;
        __syncthreads();
        if (wv == 0) {
            float t = 0.f;
#pragma unroll
            for (int w = 0; w < 8; ++w) t += pb[w * 64 + ln];
            out_probs[(size_t)b * 64 + ln] = t;
        }
    }

    // ---- write final psi ----
    float* dst = out_psi + (size_t)b * 4096 + (ln << 6) + (wv << 3);
    ((float4*)dst)[0] = make_float4(V[0].x, V[0].y, V[1].x, V[1].y);
    ((float4*)dst)[1] = make_float4(V[2].x, V[2].y, V[3].x, V[3].y);
}

extern "C" void kernel_launch(void* const* d_in, const int* in_sizes, int n_in,
                              void* d_out, int out_size, void* d_ws, size_t ws_size,
                              hipStream_t stream) {
    const float* psi = (const float*)d_in[0];
    const int*   inp = (const int*)d_in[1];
    const float* ut  = (const float*)d_in[2];
    const float* nt  = (const float*)d_in[3];

    const int B = in_sizes[0] >> 12;          // 4096 amplitudes per state
    float* probs = (float*)d_out;             // (B, 64) first
    float* opsi  = probs + (size_t)B * 64;    // then (B, 4096)

    rvqe_kernel<<<B, 512, 0, stream>>>(psi, inp, ut, nt, probs, opsi);
}